// Round 1
// baseline (125.544 us; speedup 1.0000x reference)
//
#include <hip/hip_runtime.h>
#include <math.h>

// Chamfer distance, B=4, N=M=8192, fp32.
// Output layout (flat float32): dist1[B*N], dist2[B*M], idx1[B*N] (as float),
// idx2[B*M] (as float).
//
// R10: R9 structure (memset init + proven main/final split), with ONE change
// in main's K-loop: explicit register double-buffering of the 8-point ref
// group. R9's VGPR_Count=32 showed the compiler squeezed liveness so hard it
// could not software-pipeline the 6x ds_read_b128 per j8 group -> ~120 cy of
// LDS latency exposed at the top of every j8, phase-locked across the 16
// identical waves/CU. Manual 2x unroll with named ping-pong registers
// (a0..a5 / b0..b5; named vars so nothing is runtime-indexed -> no scratch)
// prefetches group j8+1 while computing group j8. LDS is padded by 24 floats
// so the tail prefetch never reads out of bounds. Compute expression,
// processing order (strict <, earliest group wins), epilogue recompute and
// u64 atomicMin are byte-identical to R9 -> same bitwise results.
//
// Semantics: d = fmaf(dx,dx,fmaf(dy,dy,dz*dz)) (rounding delta ~ulp(d) vs
// reference, flip-safe: ~2300x below typical top-2 gaps -> absmax 0 measured
// in R5-R9). Group-of-8 min tree + strict < keeps earliest group; winner
// resolved by deterministic recompute (bitwise-identical d), descending scan
// -> smallest index; u64 atomicMin of (dist_bits<<32|idx) tie-breaks to
// lower global index == np.argmin first-occurrence.

#define QPT 4         // queries per thread
#define BLK 256       // threads per block
#define QPB (QPT*BLK) // queries per block = 1024

// process one 8-point group held in named float4 registers F0..F5
#define COMPUTE8(F0,F1,F2,F3,F4,F5,GRP) do {                                  \
    float px[8] = { F0.x, F0.w, F1.z, F2.y, F3.x, F3.w, F4.z, F5.y };         \
    float py[8] = { F0.y, F1.x, F1.w, F2.z, F3.y, F4.x, F4.w, F5.z };         \
    float pz[8] = { F0.z, F1.y, F2.x, F2.w, F3.z, F4.y, F5.x, F5.w };         \
    _Pragma("unroll")                                                         \
    for (int k = 0; k < QPT; ++k) {                                           \
        float d[8];                                                           \
        _Pragma("unroll")                                                     \
        for (int p = 0; p < 8; ++p) {                                         \
            float dx = qx[k] - px[p];                                         \
            float dy = qy[k] - py[p];                                         \
            float dz = qz[k] - pz[p];                                         \
            d[p] = fmaf(dx, dx, fmaf(dy, dy, dz * dz));                       \
        }                                                                     \
        float m01 = fminf(d[0], d[1]);                                        \
        float m23 = fminf(d[2], d[3]);                                        \
        float m45 = fminf(d[4], d[5]);                                        \
        float m67 = fminf(d[6], d[7]);                                        \
        float m = fminf(fminf(m01, m23), fminf(m45, m67));                    \
        if (m < bd[k]) { bd[k] = m; gi[k] = (GRP); }                          \
    }                                                                         \
} while (0)

__global__ __launch_bounds__(256, 4) void chamfer_main(
    const float* __restrict__ xyz1, const float* __restrict__ xyz2,
    unsigned long long* __restrict__ pp,
    int N, int M, int B, int S, int C)
{
    const int dir = blockIdx.z;          // 0: xyz1->xyz2, 1: xyz2->xyz1
    const float* q = dir ? xyz2 : xyz1;  // query cloud
    const float* r = dir ? xyz1 : xyz2;  // reference cloud
    const int Nq = dir ? M : N;
    const int Nr = dir ? N : M;
    const int b     = blockIdx.y / S;
    const int split = blockIdx.y % S;
    const int base  = split * C;         // this block's ref-index range [base, base+C)

    extern __shared__ float s[];         // C*3 floats (+24 floats prefetch slack)

    // cooperative vectorized tile load (C%8==0 -> byte count divisible by 16)
    {
        const float4* gv = (const float4*)(r + ((size_t)b * Nr + base) * 3);
        float4* sv = (float4*)s;
        const int elems4 = C * 3 / 4;
        for (int t = threadIdx.x; t < elems4; t += BLK) sv[t] = gv[t];
    }
    __syncthreads();

    // load 4 query points (stride-BLK within the block's query window)
    float qx[QPT], qy[QPT], qz[QPT];
    int qi[QPT];
    bool qv[QPT];
#pragma unroll
    for (int k = 0; k < QPT; ++k) {
        qi[k] = blockIdx.x * QPB + k * BLK + threadIdx.x;
        qv[k] = qi[k] < Nq;
        const float* qp = q + ((size_t)b * Nq + (qv[k] ? qi[k] : 0)) * 3;
        qx[k] = qp[0]; qy[k] = qp[1]; qz[k] = qp[2];
    }

    // per-query running min + winning 8-group id
    float bd[QPT];
    int   gi[QPT];
#pragma unroll
    for (int k = 0; k < QPT; ++k) { bd[k] = INFINITY; gi[k] = 0; }

    const float4* sv = (const float4*)s;
    const int iters = C / 8;

    // register double-buffered main loop: prefetch group j8+1 (and j8+2)
    // while computing the group already in registers. The final prefetch
    // (j8+2 == iters) reads the 24-float LDS slack — loaded, never used.
    float4 a0, a1, a2, a3, a4, a5, b0, b1, b2, b3, b4, b5;
    a0 = sv[0]; a1 = sv[1]; a2 = sv[2]; a3 = sv[3]; a4 = sv[4]; a5 = sv[5];
    int j8 = 0;
    for (; j8 + 2 <= iters; j8 += 2) {
        const float4* pb = sv + 6 * (j8 + 1);
        b0 = pb[0]; b1 = pb[1]; b2 = pb[2]; b3 = pb[3]; b4 = pb[4]; b5 = pb[5];
        COMPUTE8(a0, a1, a2, a3, a4, a5, j8);
        const float4* pa = sv + 6 * (j8 + 2);
        a0 = pa[0]; a1 = pa[1]; a2 = pa[2]; a3 = pa[3]; a4 = pa[4]; a5 = pa[5];
        COMPUTE8(b0, b1, b2, b3, b4, b5, j8 + 1);
    }
    if (j8 < iters) {  // odd-iters tail (not hit for C=256, kept for generality)
        COMPUTE8(a0, a1, a2, a3, a4, a5, j8);
    }

    // resolve intra-group index of the winner by deterministic recompute
    // (same fmaf expression on the same LDS data -> bitwise identical d),
    // then fold into the global per-query slot via u64 atomicMin.
    const size_t obase = (size_t)(dir * B + b) * Nq;
#pragma unroll
    for (int k = 0; k < QPT; ++k) {
        if (!qv[k]) continue;
        const int g = gi[k];
        float4 f0 = sv[6 * g + 0];
        float4 f1 = sv[6 * g + 1];
        float4 f2 = sv[6 * g + 2];
        float4 f3 = sv[6 * g + 3];
        float4 f4 = sv[6 * g + 4];
        float4 f5 = sv[6 * g + 5];
        float px[8] = { f0.x, f0.w, f1.z, f2.y, f3.x, f3.w, f4.z, f5.y };
        float py[8] = { f0.y, f1.x, f1.w, f2.z, f3.y, f4.x, f4.w, f5.z };
        float pz[8] = { f0.z, f1.y, f2.x, f2.w, f3.z, f4.y, f5.x, f5.w };
        int best = 0;
#pragma unroll
        for (int p = 7; p >= 0; --p) {   // descending: ends at SMALLEST match
            float dx = qx[k] - px[p];
            float dy = qy[k] - py[p];
            float dz = qz[k] - pz[p];
            float d = fmaf(dx, dx, fmaf(dy, dy, dz * dz));
            if (d == bd[k]) best = p;    // match guaranteed (same bits)
        }
        const int idx = base + g * 8 + best;
        // d >= 0 -> float bits order-monotonic as unsigned.
        unsigned long long packed =
            ((unsigned long long)__float_as_uint(bd[k]) << 32) | (unsigned)idx;
        atomicMin(&pp[obase + qi[k]], packed);
    }
}

__global__ __launch_bounds__(256) void chamfer_final(
    const unsigned long long* __restrict__ pp,
    float* __restrict__ out, int N, int M, int B)
{
    const int gid = blockIdx.x * blockDim.x + threadIdx.x;
    const int perDir0 = B * N;
    int dir, rem;
    if (gid < perDir0) { dir = 0; rem = gid; }
    else if (gid < perDir0 + B * M) { dir = 1; rem = gid - perDir0; }
    else return;
    const int Nq = dir ? M : N;

    // pp is [2][B][Nq] flat; rem = b*Nq + i
    unsigned long long v = pp[(size_t)(dir * B) * Nq + rem];

    float* dist_out = out + (dir ? (size_t)B * N : 0);
    float* idx_out  = out + (size_t)B * N + (size_t)B * M + (dir ? (size_t)B * N : 0);
    dist_out[rem] = __uint_as_float((unsigned)(v >> 32));
    idx_out[rem]  = (float)(unsigned)(v & 0xffffffffu);
}

extern "C" void kernel_launch(void* const* d_in, const int* in_sizes, int n_in,
                              void* d_out, int out_size, void* d_ws, size_t ws_size,
                              hipStream_t stream) {
    const float* xyz1 = (const float*)d_in[0];
    const float* xyz2 = (const float*)d_in[1];
    float* out = (float*)d_out;
    const int B = 4;
    const int N = in_sizes[0] / (B * 3);
    const int M = in_sizes[1] / (B * 3);
    const int NQ = (N > M ? N : M);
    const int NR = (N > M ? N : M);

    int S = 32;
    while (NR % (S * 8)) S >>= 1;  // need C = NR/S divisible by 8
    const int C = NR / S;

    unsigned long long* pp = (unsigned long long*)d_ws;  // [2][B][NQ] packed slots
    const int nslots = 2 * B * NQ;

    // init pp to ~0ULL via byte-pattern memset (0xFF) — graph-capturable
    // memset node, replaces the init kernel (one fewer dispatch + gap).
    hipMemsetAsync(pp, 0xFF, (size_t)nslots * 8, stream);

    dim3 grid((NQ + QPB - 1) / QPB, B * S, 2);
    // +24 floats of slack so the register-pipeline's tail prefetch stays in bounds
    size_t lds = (size_t)(C * 3 + 24) * sizeof(float);
    chamfer_main<<<grid, dim3(BLK, 1, 1), lds, stream>>>(
        xyz1, xyz2, pp, N, M, B, S, C);

    chamfer_final<<<dim3((nslots + 255) / 256, 1, 1), dim3(256, 1, 1), 0, stream>>>(
        pp, out, N, M, B);
}

// Round 2
// 122.635 us; speedup vs baseline: 1.0237x; 1.0237x over previous
//
#include <hip/hip_runtime.h>
#include <math.h>

// Chamfer distance, B=4, N=M=8192, fp32.
// Output layout (flat float32): dist1[B*N], dist2[B*M], idx1[B*N] (as float),
// idx2[B*M] (as float).
//
// R11: R9 main-loop structure (R10's register double-buffer was neutral ->
// reverted), with the winner-resolve MOVED OUT of chamfer_main. R9's 4.31M
// LDS bank-conflict cycles (~9% of kernel) came from the epilogue's divergent
// group re-gather (96B-strided float4 reads -> 4 distinct bank-starts ->
// ~16-way conflicts). Now chamfer_main atomicMins (dist_bits<<32 | group_id)
// — no LDS re-read, no recompute — and chamfer_final (65K threads, trivial)
// resolves the intra-group index by the same deterministic fmaf recompute
// from GLOBAL memory (identical bits to the LDS copy).
//
// Tie semantics unchanged vs R9: equal dist bits -> atomicMin picks the
// smallest global group id; the smallest index attaining the min lies in the
// smallest such group (groups partition the index space in order); within
// the group the descending scan ends at the smallest matching p. Result is
// bitwise identical to R9's (bits<<32|idx) scheme == np.argmin
// first-occurrence.
//
// Min-of-8 restructured as fminf(fminf(a,b),c) triples -> v_min3 x3 + v_min
// (4 instrs vs ~6): exact min, no rounding, same strict-< earliest-group
// update order.
//
// Semantics: d = fmaf(dx,dx,fmaf(dy,dy,dz*dz)) (rounding delta ~ulp(d) vs
// reference, flip-safe: ~2300x below typical top-2 gaps -> absmax 0 measured
// R5-R10).

#define QPT 4         // queries per thread
#define BLK 256       // threads per block
#define QPB (QPT*BLK) // queries per block = 1024

__global__ __launch_bounds__(256, 4) void chamfer_main(
    const float* __restrict__ xyz1, const float* __restrict__ xyz2,
    unsigned long long* __restrict__ pp,
    int N, int M, int B, int S, int C)
{
    const int dir = blockIdx.z;          // 0: xyz1->xyz2, 1: xyz2->xyz1
    const float* q = dir ? xyz2 : xyz1;  // query cloud
    const float* r = dir ? xyz1 : xyz2;  // reference cloud
    const int Nq = dir ? M : N;
    const int Nr = dir ? N : M;
    const int b     = blockIdx.y / S;
    const int split = blockIdx.y % S;
    const int base  = split * C;         // this block's ref-index range [base, base+C)

    extern __shared__ float s[];         // C*3 floats

    // cooperative vectorized tile load (C%8==0 -> byte count divisible by 16)
    {
        const float4* gv = (const float4*)(r + ((size_t)b * Nr + base) * 3);
        float4* sv = (float4*)s;
        const int elems4 = C * 3 / 4;
        for (int t = threadIdx.x; t < elems4; t += BLK) sv[t] = gv[t];
    }
    __syncthreads();

    // load 4 query points (stride-BLK within the block's query window)
    float qx[QPT], qy[QPT], qz[QPT];
    int qi[QPT];
    bool qv[QPT];
#pragma unroll
    for (int k = 0; k < QPT; ++k) {
        qi[k] = blockIdx.x * QPB + k * BLK + threadIdx.x;
        qv[k] = qi[k] < Nq;
        const float* qp = q + ((size_t)b * Nq + (qv[k] ? qi[k] : 0)) * 3;
        qx[k] = qp[0]; qy[k] = qp[1]; qz[k] = qp[2];
    }

    // per-query running min + winning 8-group id (block-local)
    float bd[QPT];
    int   gi[QPT];
#pragma unroll
    for (int k = 0; k < QPT; ++k) { bd[k] = INFINITY; gi[k] = 0; }

    const float4* sv = (const float4*)s;
    const int iters = C / 8;
    for (int j8 = 0; j8 < iters; ++j8) {
        // 24 floats = 8 ref points; all lanes same address -> LDS broadcast
        float4 f0 = sv[6 * j8 + 0];
        float4 f1 = sv[6 * j8 + 1];
        float4 f2 = sv[6 * j8 + 2];
        float4 f3 = sv[6 * j8 + 3];
        float4 f4 = sv[6 * j8 + 4];
        float4 f5 = sv[6 * j8 + 5];
        float px[8] = { f0.x, f0.w, f1.z, f2.y, f3.x, f3.w, f4.z, f5.y };
        float py[8] = { f0.y, f1.x, f1.w, f2.z, f3.y, f4.x, f4.w, f5.z };
        float pz[8] = { f0.z, f1.y, f2.x, f2.w, f3.z, f4.y, f5.x, f5.w };
#pragma unroll
        for (int k = 0; k < QPT; ++k) {
            float d[8];
#pragma unroll
            for (int p = 0; p < 8; ++p) {
                float dx = qx[k] - px[p];
                float dy = qy[k] - py[p];
                float dz = qz[k] - pz[p];
                d[p] = fmaf(dx, dx, fmaf(dy, dy, dz * dz));
            }
            // min-of-8 as min3 x3 + min (exact; value independent of tree shape)
            float t0 = fminf(fminf(d[0], d[1]), d[2]);
            float t1 = fminf(fminf(d[3], d[4]), d[5]);
            float t2 = fminf(fminf(d[6], d[7]), t0);
            float m  = fminf(t1, t2);
            // strict < keeps the EARLIEST group attaining the min value
            if (m < bd[k]) { bd[k] = m; gi[k] = j8; }
        }
    }

    // fold (dist_bits, global group id) into the per-query slot.
    // d >= 0 -> float bits order-monotonic as unsigned; low 32 bits carry the
    // group id so equal-dist ties resolve to the smallest group == smallest
    // global index's group.
    const size_t obase = (size_t)(dir * B + b) * Nq;
    const int gbase = split * (C / 8);   // global group base for this block
#pragma unroll
    for (int k = 0; k < QPT; ++k) {
        if (!qv[k]) continue;
        unsigned long long packed =
            ((unsigned long long)__float_as_uint(bd[k]) << 32)
            | (unsigned)(gbase + gi[k]);
        atomicMin(&pp[obase + qi[k]], packed);
    }
}

__global__ __launch_bounds__(256) void chamfer_final(
    const float* __restrict__ xyz1, const float* __restrict__ xyz2,
    const unsigned long long* __restrict__ pp,
    float* __restrict__ out, int N, int M, int B)
{
    const int gid = blockIdx.x * blockDim.x + threadIdx.x;
    const int perDir0 = B * N;
    int dir, rem;
    if (gid < perDir0) { dir = 0; rem = gid; }
    else if (gid < perDir0 + B * M) { dir = 1; rem = gid - perDir0; }
    else return;
    const int Nq = dir ? M : N;
    const int Nr = dir ? N : M;
    const float* q = dir ? xyz2 : xyz1;
    const float* r = dir ? xyz1 : xyz2;

    // pp is [2][B][Nq] flat; rem = b*Nq + i
    unsigned long long v = pp[(size_t)(dir * B) * Nq + rem];
    const unsigned bits = (unsigned)(v >> 32);
    const int grp = (int)(v & 0xffffffffu);

    const int b  = rem / Nq;
    const int qi = rem - b * Nq;
    const float* qp = q + ((size_t)b * Nq + qi) * 3;
    const float qx = qp[0], qy = qp[1], qz = qp[2];

    // gather the winning 8-point group from global (L2-resident), recompute
    // with the SAME fmaf expression on the SAME input bits -> bitwise match.
    const float4* rv = (const float4*)(r + ((size_t)b * Nr + (size_t)grp * 8) * 3);
    float4 f0 = rv[0], f1 = rv[1], f2 = rv[2], f3 = rv[3], f4 = rv[4], f5 = rv[5];
    float px[8] = { f0.x, f0.w, f1.z, f2.y, f3.x, f3.w, f4.z, f5.y };
    float py[8] = { f0.y, f1.x, f1.w, f2.z, f3.y, f4.x, f4.w, f5.z };
    float pz[8] = { f0.z, f1.y, f2.x, f2.w, f3.z, f4.y, f5.x, f5.w };
    int best = 0;
#pragma unroll
    for (int p = 7; p >= 0; --p) {       // descending: ends at SMALLEST match
        float dx = qx - px[p];
        float dy = qy - py[p];
        float dz = qz - pz[p];
        float d = fmaf(dx, dx, fmaf(dy, dy, dz * dz));
        if (__float_as_uint(d) == bits) best = p;  // match guaranteed (same bits)
    }
    const int idx = grp * 8 + best;

    float* dist_out = out + (dir ? (size_t)B * N : 0);
    float* idx_out  = out + (size_t)B * N + (size_t)B * M + (dir ? (size_t)B * N : 0);
    dist_out[rem] = __uint_as_float(bits);
    idx_out[rem]  = (float)idx;
}

extern "C" void kernel_launch(void* const* d_in, const int* in_sizes, int n_in,
                              void* d_out, int out_size, void* d_ws, size_t ws_size,
                              hipStream_t stream) {
    const float* xyz1 = (const float*)d_in[0];
    const float* xyz2 = (const float*)d_in[1];
    float* out = (float*)d_out;
    const int B = 4;
    const int N = in_sizes[0] / (B * 3);
    const int M = in_sizes[1] / (B * 3);
    const int NQ = (N > M ? N : M);
    const int NR = (N > M ? N : M);

    int S = 32;
    while (NR % (S * 8)) S >>= 1;  // need C = NR/S divisible by 8
    const int C = NR / S;

    unsigned long long* pp = (unsigned long long*)d_ws;  // [2][B][NQ] packed slots
    const int nslots = 2 * B * NQ;

    // init pp to ~0ULL via byte-pattern memset (0xFF) — graph-capturable
    // memset node, replaces the init kernel (one fewer dispatch + gap).
    hipMemsetAsync(pp, 0xFF, (size_t)nslots * 8, stream);

    dim3 grid((NQ + QPB - 1) / QPB, B * S, 2);
    size_t lds = (size_t)C * 3 * sizeof(float);
    chamfer_main<<<grid, dim3(BLK, 1, 1), lds, stream>>>(
        xyz1, xyz2, pp, N, M, B, S, C);

    chamfer_final<<<dim3((nslots + 255) / 256, 1, 1), dim3(256, 1, 1), 0, stream>>>(
        xyz1, xyz2, pp, out, N, M, B);
}

// Round 3
// 118.771 us; speedup vs baseline: 1.0570x; 1.0325x over previous
//
#include <hip/hip_runtime.h>
#include <math.h>

// Chamfer distance, B=4, N=M=8192, fp32.
// Output layout (flat float32): dist1[B*N], dist2[B*M], idx1[B*N] (as float),
// idx2[B*M] (as float).
//
// R12: R11 verbatim except __launch_bounds__(256,4) -> (256,8).
// R11 eliminated all LDS bank conflicts (4.31M -> 0) by moving winner-resolve
// to chamfer_final; main is now pure VALU-issue-bound (HBM 3%, conflicts 0)
// at ~66% of the 49us issue floor with only 16 waves/CU (4/SIMD) resident —
// pinned by the old launch bound. 8 waves/SIMD fits easily (VGPR 32 <= 64,
// LDS 3KB x 8 = 24KB) and the 2048-block grid is exactly 256 CU x 8 ->
// all blocks co-resident. More TLP fills the lgkmcnt/branch issue bubbles
// that 4 phase-similar waves/SIMD could not. No semantic change: per-wave
// visit order, arithmetic, tie-breaking all identical -> bitwise outputs.
//
// Tie semantics (unchanged): equal dist bits -> atomicMin picks the smallest
// global group id (groups partition index space in order); within the group
// the descending scan ends at the smallest matching p == np.argmin
// first-occurrence.
//
// Semantics: d = fmaf(dx,dx,fmaf(dy,dy,dz*dz)) (rounding delta ~ulp(d) vs
// reference, flip-safe: ~2300x below typical top-2 gaps -> absmax 0 measured
// R5-R11).

#define QPT 4         // queries per thread
#define BLK 256       // threads per block
#define QPB (QPT*BLK) // queries per block = 1024

__global__ __launch_bounds__(256, 8) void chamfer_main(
    const float* __restrict__ xyz1, const float* __restrict__ xyz2,
    unsigned long long* __restrict__ pp,
    int N, int M, int B, int S, int C)
{
    const int dir = blockIdx.z;          // 0: xyz1->xyz2, 1: xyz2->xyz1
    const float* q = dir ? xyz2 : xyz1;  // query cloud
    const float* r = dir ? xyz1 : xyz2;  // reference cloud
    const int Nq = dir ? M : N;
    const int Nr = dir ? N : M;
    const int b     = blockIdx.y / S;
    const int split = blockIdx.y % S;
    const int base  = split * C;         // this block's ref-index range [base, base+C)

    extern __shared__ float s[];         // C*3 floats

    // cooperative vectorized tile load (C%8==0 -> byte count divisible by 16)
    {
        const float4* gv = (const float4*)(r + ((size_t)b * Nr + base) * 3);
        float4* sv = (float4*)s;
        const int elems4 = C * 3 / 4;
        for (int t = threadIdx.x; t < elems4; t += BLK) sv[t] = gv[t];
    }
    __syncthreads();

    // load 4 query points (stride-BLK within the block's query window)
    float qx[QPT], qy[QPT], qz[QPT];
    int qi[QPT];
    bool qv[QPT];
#pragma unroll
    for (int k = 0; k < QPT; ++k) {
        qi[k] = blockIdx.x * QPB + k * BLK + threadIdx.x;
        qv[k] = qi[k] < Nq;
        const float* qp = q + ((size_t)b * Nq + (qv[k] ? qi[k] : 0)) * 3;
        qx[k] = qp[0]; qy[k] = qp[1]; qz[k] = qp[2];
    }

    // per-query running min + winning 8-group id (block-local)
    float bd[QPT];
    int   gi[QPT];
#pragma unroll
    for (int k = 0; k < QPT; ++k) { bd[k] = INFINITY; gi[k] = 0; }

    const float4* sv = (const float4*)s;
    const int iters = C / 8;
    for (int j8 = 0; j8 < iters; ++j8) {
        // 24 floats = 8 ref points; all lanes same address -> LDS broadcast
        float4 f0 = sv[6 * j8 + 0];
        float4 f1 = sv[6 * j8 + 1];
        float4 f2 = sv[6 * j8 + 2];
        float4 f3 = sv[6 * j8 + 3];
        float4 f4 = sv[6 * j8 + 4];
        float4 f5 = sv[6 * j8 + 5];
        float px[8] = { f0.x, f0.w, f1.z, f2.y, f3.x, f3.w, f4.z, f5.y };
        float py[8] = { f0.y, f1.x, f1.w, f2.z, f3.y, f4.x, f4.w, f5.z };
        float pz[8] = { f0.z, f1.y, f2.x, f2.w, f3.z, f4.y, f5.x, f5.w };
#pragma unroll
        for (int k = 0; k < QPT; ++k) {
            float d[8];
#pragma unroll
            for (int p = 0; p < 8; ++p) {
                float dx = qx[k] - px[p];
                float dy = qy[k] - py[p];
                float dz = qz[k] - pz[p];
                d[p] = fmaf(dx, dx, fmaf(dy, dy, dz * dz));
            }
            // min-of-8 as min3 x3 + min (exact; value independent of tree shape)
            float t0 = fminf(fminf(d[0], d[1]), d[2]);
            float t1 = fminf(fminf(d[3], d[4]), d[5]);
            float t2 = fminf(fminf(d[6], d[7]), t0);
            float m  = fminf(t1, t2);
            // strict < keeps the EARLIEST group attaining the min value
            if (m < bd[k]) { bd[k] = m; gi[k] = j8; }
        }
    }

    // fold (dist_bits, global group id) into the per-query slot.
    // d >= 0 -> float bits order-monotonic as unsigned; low 32 bits carry the
    // group id so equal-dist ties resolve to the smallest group == smallest
    // global index's group.
    const size_t obase = (size_t)(dir * B + b) * Nq;
    const int gbase = split * (C / 8);   // global group base for this block
#pragma unroll
    for (int k = 0; k < QPT; ++k) {
        if (!qv[k]) continue;
        unsigned long long packed =
            ((unsigned long long)__float_as_uint(bd[k]) << 32)
            | (unsigned)(gbase + gi[k]);
        atomicMin(&pp[obase + qi[k]], packed);
    }
}

__global__ __launch_bounds__(256) void chamfer_final(
    const float* __restrict__ xyz1, const float* __restrict__ xyz2,
    const unsigned long long* __restrict__ pp,
    float* __restrict__ out, int N, int M, int B)
{
    const int gid = blockIdx.x * blockDim.x + threadIdx.x;
    const int perDir0 = B * N;
    int dir, rem;
    if (gid < perDir0) { dir = 0; rem = gid; }
    else if (gid < perDir0 + B * M) { dir = 1; rem = gid - perDir0; }
    else return;
    const int Nq = dir ? M : N;
    const int Nr = dir ? N : M;
    const float* q = dir ? xyz2 : xyz1;
    const float* r = dir ? xyz1 : xyz2;

    // pp is [2][B][Nq] flat; rem = b*Nq + i
    unsigned long long v = pp[(size_t)(dir * B) * Nq + rem];
    const unsigned bits = (unsigned)(v >> 32);
    const int grp = (int)(v & 0xffffffffu);

    const int b  = rem / Nq;
    const int qi = rem - b * Nq;
    const float* qp = q + ((size_t)b * Nq + qi) * 3;
    const float qx = qp[0], qy = qp[1], qz = qp[2];

    // gather the winning 8-point group from global (L2-resident), recompute
    // with the SAME fmaf expression on the SAME input bits -> bitwise match.
    const float4* rv = (const float4*)(r + ((size_t)b * Nr + (size_t)grp * 8) * 3);
    float4 f0 = rv[0], f1 = rv[1], f2 = rv[2], f3 = rv[3], f4 = rv[4], f5 = rv[5];
    float px[8] = { f0.x, f0.w, f1.z, f2.y, f3.x, f3.w, f4.z, f5.y };
    float py[8] = { f0.y, f1.x, f1.w, f2.z, f3.y, f4.x, f4.w, f5.z };
    float pz[8] = { f0.z, f1.y, f2.x, f2.w, f3.z, f4.y, f5.x, f5.w };
    int best = 0;
#pragma unroll
    for (int p = 7; p >= 0; --p) {       // descending: ends at SMALLEST match
        float dx = qx - px[p];
        float dy = qy - py[p];
        float dz = qz - pz[p];
        float d = fmaf(dx, dx, fmaf(dy, dy, dz * dz));
        if (__float_as_uint(d) == bits) best = p;  // match guaranteed (same bits)
    }
    const int idx = grp * 8 + best;

    float* dist_out = out + (dir ? (size_t)B * N : 0);
    float* idx_out  = out + (size_t)B * N + (size_t)B * M + (dir ? (size_t)B * N : 0);
    dist_out[rem] = __uint_as_float(bits);
    idx_out[rem]  = (float)idx;
}

extern "C" void kernel_launch(void* const* d_in, const int* in_sizes, int n_in,
                              void* d_out, int out_size, void* d_ws, size_t ws_size,
                              hipStream_t stream) {
    const float* xyz1 = (const float*)d_in[0];
    const float* xyz2 = (const float*)d_in[1];
    float* out = (float*)d_out;
    const int B = 4;
    const int N = in_sizes[0] / (B * 3);
    const int M = in_sizes[1] / (B * 3);
    const int NQ = (N > M ? N : M);
    const int NR = (N > M ? N : M);

    int S = 32;
    while (NR % (S * 8)) S >>= 1;  // need C = NR/S divisible by 8
    const int C = NR / S;

    unsigned long long* pp = (unsigned long long*)d_ws;  // [2][B][NQ] packed slots
    const int nslots = 2 * B * NQ;

    // init pp to ~0ULL via byte-pattern memset (0xFF) — graph-capturable
    // memset node, replaces the init kernel (one fewer dispatch + gap).
    hipMemsetAsync(pp, 0xFF, (size_t)nslots * 8, stream);

    dim3 grid((NQ + QPB - 1) / QPB, B * S, 2);
    size_t lds = (size_t)C * 3 * sizeof(float);
    chamfer_main<<<grid, dim3(BLK, 1, 1), lds, stream>>>(
        xyz1, xyz2, pp, N, M, B, S, C);

    chamfer_final<<<dim3((nslots + 255) / 256, 1, 1), dim3(256, 1, 1), 0, stream>>>(
        xyz1, xyz2, pp, out, N, M, B);
}